// Round 6
// baseline (391.278 us; speedup 1.0000x reference)
//
#include <hip/hip_runtime.h>

#define N_NODES 100000
#define W_INF   256
#define W_OUTF  64
#define C_CH    2
#define T_ET    4
#define E_EDGE  800000
#define NUM_CLS 4
#define M_TGT   20000
#define BETA    0.5f
#define MAXDEG  96

typedef __attribute__((ext_vector_type(8))) short bf16x8;
typedef __attribute__((ext_vector_type(4))) float floatx4;

__device__ inline short f2bf(float f) {
    unsigned u = __builtin_bit_cast(unsigned, f);
    u += 0x7FFF + ((u >> 16) & 1);          // RNE
    return (short)(u >> 16);
}

// ---------- filt = softmax(conv_weight, axis=1) ----------
__global__ void softmax_filt_kernel(const float* __restrict__ conv_weight,
                                    float* __restrict__ filt) {
    int c = threadIdx.x;
    if (c < C_CH) {
        float mx = -1e30f;
        for (int t = 0; t < T_ET; t++) mx = fmaxf(mx, conv_weight[c * T_ET + t]);
        float e[T_ET];
        float s = 0.f;
        for (int t = 0; t < T_ET; t++) { e[t] = expf(conv_weight[c * T_ET + t] - mx); s += e[t]; }
        for (int t = 0; t < T_ET; t++) filt[c * T_ET + t] = e[t] / s;
    }
}

// ---------- Bt[co][k] = bf16(Ws[c][k][o]), co = c*64+o ----------
__global__ void wcvt_kernel(const float* __restrict__ Ws, short* __restrict__ Bt) {
    int i = blockIdx.x * 256 + threadIdx.x;
    if (i < C_CH * W_OUTF * W_INF) {
        int co = i >> 8, k = i & 255;
        int c = co >> 6, o = co & 63;
        Bt[i] = f2bf(Ws[((size_t)c * W_INF + k) * W_OUTF + o]);
    }
}

// ---------- mark rid[target_x[i]] = -2 (rid pre-memset to -1) ----------
__global__ void mark_kernel(const int* __restrict__ target_x, int* __restrict__ rid) {
    int i = blockIdx.x * blockDim.x + threadIdx.x;
    if (i < M_TGT) rid[target_x[i]] = -2;
}

// ---------- compact flagged rows ----------
__global__ void compact_kernel(int* __restrict__ rid, int* __restrict__ row_list,
                               int* __restrict__ nrows) {
    int n = blockIdx.x * blockDim.x + threadIdx.x;
    if (n < N_NODES && rid[n] == -2) {
        int id = atomicAdd(nrows, 1);
        rid[n] = id;
        row_list[id] = n;
    }
}

// ---------- fused build: bin flagged edges into fixed-stride rows ----------
// records[id*MAXDEG + p] = (ev_bits<<32) | col | (t<<20); counts[id] = degree.
__global__ void build_kernel(const int* __restrict__ edge_index,
                             const float* __restrict__ edge_value,
                             const int* __restrict__ rid,
                             int* __restrict__ counts,
                             unsigned long long* __restrict__ records) {
    int t = blockIdx.y;
    int i = blockIdx.x * 256 + threadIdx.x;          // oct-edge index
    if (i >= E_EDGE / 8) return;
    int e = i * 8;
    const int*   rbase = &edge_index[(size_t)(t * 2 + 0) * E_EDGE + e];
    const int*   cbase = &edge_index[(size_t)(t * 2 + 1) * E_EDGE + e];
    const float* vbase = &edge_value[(size_t)t * E_EDGE + e];
    int4   r4a = *(const int4*)  &rbase[0], r4b = *(const int4*)  &rbase[4];
    int4   c4a = *(const int4*)  &cbase[0], c4b = *(const int4*)  &cbase[4];
    float4 v4a = *(const float4*)&vbase[0], v4b = *(const float4*)&vbase[4];
    int rows[8] = {r4a.x, r4a.y, r4a.z, r4a.w, r4b.x, r4b.y, r4b.z, r4b.w};
    int cols[8] = {c4a.x, c4a.y, c4a.z, c4a.w, c4b.x, c4b.y, c4b.z, c4b.w};
    float evv[8] = {v4a.x, v4a.y, v4a.z, v4a.w, v4b.x, v4b.y, v4b.z, v4b.w};
    int ids[8];
    #pragma unroll
    for (int j = 0; j < 8; j++) ids[j] = rid[rows[j]];
    #pragma unroll
    for (int j = 0; j < 8; j++) {
        if (ids[j] >= 0) {
            int p = atomicAdd(&counts[ids[j]], 1);
            if (p < MAXDEG) {
                unsigned long long rec =
                    (unsigned long long)(unsigned)(cols[j] | (t << 20)) |
                    ((unsigned long long)__float_as_uint(evv[j]) << 32);
                records[(size_t)ids[j] * MAXDEG + p] = rec;
            }
        }
    }
}

// ---------- gather: Hc[c][row][lane] = sum_p ev*filt[c][t] * Xp[c][col][lane] ----------
// 4 waves: (half, c) = (tid>>7, (tid>>6)&1). Each wave sums half the records.
__global__ void gather_kernel(const int* __restrict__ row_list,
                              const int* __restrict__ counts,
                              const unsigned long long* __restrict__ records,
                              const float* __restrict__ filt,
                              const float* __restrict__ Xp,
                              float* __restrict__ Hc,
                              const int* __restrict__ nrows_ptr) {
    __shared__ float part[C_CH][64];
    int b = blockIdx.x;
    if (b >= *nrows_ptr) return;
    int tid = threadIdx.x;
    int c = (tid >> 6) & 1, half = tid >> 7, lane = tid & 63;
    float f[T_ET];
    #pragma unroll
    for (int t = 0; t < T_ET; t++) f[t] = filt[c * T_ET + t];
    int n = row_list[b];
    int cnt = counts[b]; if (cnt > MAXDEG) cnt = MAXDEG;
    int mid = (cnt + 1) >> 1;
    int p = half ? mid : 0;
    int pe = half ? cnt : mid;
    const unsigned long long* rec = records + (size_t)b * MAXDEG;
    const float* xb = Xp + (size_t)c * N_NODES * W_OUTF + lane;
    float acc = 0.f;
    for (; p + 3 < pe; p += 4) {
        unsigned long long r0 = rec[p],     r1 = rec[p + 1];
        unsigned long long r2 = rec[p + 2], r3 = rec[p + 3];
        int k0 = (int)(unsigned)r0, k1 = (int)(unsigned)r1;
        int k2 = (int)(unsigned)r2, k3 = (int)(unsigned)r3;
        float e0 = __uint_as_float((unsigned)(r0 >> 32));
        float e1 = __uint_as_float((unsigned)(r1 >> 32));
        float e2 = __uint_as_float((unsigned)(r2 >> 32));
        float e3 = __uint_as_float((unsigned)(r3 >> 32));
        float x0 = xb[(size_t)(k0 & 0xFFFFF) * W_OUTF];
        float x1 = xb[(size_t)(k1 & 0xFFFFF) * W_OUTF];
        float x2 = xb[(size_t)(k2 & 0xFFFFF) * W_OUTF];
        float x3 = xb[(size_t)(k3 & 0xFFFFF) * W_OUTF];
        acc += e0 * f[k0 >> 20] * x0 + e1 * f[k1 >> 20] * x1
             + e2 * f[k2 >> 20] * x2 + e3 * f[k3 >> 20] * x3;
    }
    for (; p < pe; p++) {
        unsigned long long r0 = rec[p];
        int k0 = (int)(unsigned)r0;
        float e0 = __uint_as_float((unsigned)(r0 >> 32));
        acc += e0 * f[k0 >> 20] * xb[(size_t)(k0 & 0xFFFFF) * W_OUTF];
    }
    if (half) part[c][lane] = acc;
    __syncthreads();
    if (!half) {
        acc += part[c][lane];
        Hc[((size_t)c * N_NODES + n) * W_OUTF + lane] = acc;
    }
}

// ---------- LDS-free MFMA gemm: wave = 16 rows x full N=128; K=256 in 8 chunks ----------
__global__ __launch_bounds__(256, 8)
void gemm_direct_kernel(const float* __restrict__ X, const short* __restrict__ Bt,
                        float* __restrict__ Xp) {
    int tid = threadIdx.x;
    int w = tid >> 6, lane = tid & 63;
    int quad = lane >> 4, l15 = lane & 15;
    int m0 = blockIdx.x * 64 + w * 16;      // wave's 16-row strip
    int arow = m0 + l15;
    bool avalid = arow < N_NODES;
    const float* xrow = X + (size_t)(avalid ? arow : 0) * W_INF;
    floatx4 acc[8] = {};
    #pragma unroll 2
    for (int kc = 0; kc < W_INF; kc += 32) {
        int kb = kc + quad * 8;
        float4 av0 = *(const float4*)&xrow[kb];
        float4 av1 = *(const float4*)&xrow[kb + 4];
        bf16x8 a;
        a[0] = f2bf(av0.x); a[1] = f2bf(av0.y); a[2] = f2bf(av0.z); a[3] = f2bf(av0.w);
        a[4] = f2bf(av1.x); a[5] = f2bf(av1.y); a[6] = f2bf(av1.z); a[7] = f2bf(av1.w);
        #pragma unroll
        for (int nt = 0; nt < 8; nt++) {
            bf16x8 b = *(const bf16x8*)&Bt[(size_t)(nt * 16 + l15) * W_INF + kb];
            acc[nt] = __builtin_amdgcn_mfma_f32_16x16x32_bf16(a, b, acc[nt], 0, 0, 0);
        }
    }
    // D layout: col = l15 (-> co), row = quad*4 + r (-> m within strip)
    #pragma unroll
    for (int nt = 0; nt < 8; nt++) {
        int co = nt * 16 + l15;
        int c = co >> 6, o = co & 63;
        #pragma unroll
        for (int r = 0; r < 4; r++) {
            int m = m0 + quad * 4 + r;
            if (m < N_NODES)
                Xp[((size_t)c * N_NODES + m) * W_OUTF + o] = acc[nt][r];
        }
    }
}

// ---------- head: 16 targets per block; W1 staged transposed in LDS ----------
#define HTGT 16
__global__ void head_kernel(const float* __restrict__ Xp,
                            const float* __restrict__ Hc,
                            const float* __restrict__ W1,
                            const float* __restrict__ b1,
                            const float* __restrict__ linW,
                            const float* __restrict__ linb,
                            const int* __restrict__ target_x,
                            const int* __restrict__ target,
                            float* __restrict__ out) {
    __shared__ float w1s[C_CH * W_OUTF][W_OUTF + 1];
    __shared__ float hcat_s[4][C_CH * W_OUTF];
    __shared__ float loss_s[4];
    int tid = threadIdx.x;
    for (int i = tid; i < W_OUTF * C_CH * W_OUTF; i += 256) {
        int o = i >> 7, k = i & 127;
        w1s[k][o] = W1[i];
    }
    int wave = tid >> 6, lane = tid & 63;
    float l0 = linW[0 * W_OUTF + lane], l1 = linW[1 * W_OUTF + lane];
    float l2 = linW[2 * W_OUTF + lane], l3 = linW[3 * W_OUTF + lane];
    float lb0 = linb[0], lb1 = linb[1], lb2 = linb[2], lb3 = linb[3];
    float bias = b1[lane];
    float lsum = 0.f;
    __syncthreads();
    for (int it = 0; it < HTGT / 4; it++) {
        int m = blockIdx.x * HTGT + it * 4 + wave;
        int row = target_x[m];
        #pragma unroll
        for (int c = 0; c < C_CH; c++) {
            size_t idx = ((size_t)c * N_NODES + row) * W_OUTF + lane;
            float v = BETA * Xp[idx] + (1.f - BETA) * Hc[idx];
            hcat_s[wave][c * W_OUTF + lane] = fmaxf(v, 0.f);
        }
        __syncthreads();
        float acc = bias;
        #pragma unroll 8
        for (int k = 0; k < C_CH * W_OUTF; k++) acc += hcat_s[wave][k] * w1s[k][lane];
        float h2 = fmaxf(acc, 0.f);
        float p0 = l0 * h2, p1 = l1 * h2, p2 = l2 * h2, p3 = l3 * h2;
        #pragma unroll
        for (int off = 32; off > 0; off >>= 1) {
            p0 += __shfl_xor(p0, off);
            p1 += __shfl_xor(p1, off);
            p2 += __shfl_xor(p2, off);
            p3 += __shfl_xor(p3, off);
        }
        if (lane == 0) {
            float y[NUM_CLS];
            y[0] = p0 + lb0; y[1] = p1 + lb1; y[2] = p2 + lb2; y[3] = p3 + lb3;
            float mx = fmaxf(fmaxf(y[0], y[1]), fmaxf(y[2], y[3]));
            float s = 0.f;
            #pragma unroll
            for (int k = 0; k < NUM_CLS; k++) s += expf(y[k] - mx);
            float lse = mx + logf(s);
            #pragma unroll
            for (int k = 0; k < NUM_CLS; k++) out[1 + (size_t)m * NUM_CLS + k] = y[k];
            int tg = target[m];
            lsum += lse - y[tg];
        }
        __syncthreads();
    }
    if (lane == 0) loss_s[wave] = lsum;
    __syncthreads();
    if (tid == 0) {
        float L = loss_s[0] + loss_s[1] + loss_s[2] + loss_s[3];
        atomicAdd(&out[0], L * (1.0f / (float)M_TGT));
    }
}

extern "C" void kernel_launch(void* const* d_in, const int* in_sizes, int n_in,
                              void* d_out, int out_size, void* d_ws, size_t ws_size,
                              hipStream_t stream) {
    const float* X           = (const float*)d_in[0];
    const float* edge_value  = (const float*)d_in[1];
    const float* Ws          = (const float*)d_in[2];
    const float* conv_weight = (const float*)d_in[3];
    const float* linear1_W   = (const float*)d_in[4];
    const float* linear1_b   = (const float*)d_in[5];
    const float* lin_W       = (const float*)d_in[6];
    const float* lin_b       = (const float*)d_in[7];
    const int*   edge_index  = (const int*)d_in[8];
    const int*   target_x    = (const int*)d_in[9];
    const int*   target      = (const int*)d_in[10];
    float* out = (float*)d_out;

    char* ws = (char*)d_ws;
    size_t off = 0;
    float* filt  = (float*)(ws + off); off += 256;
    size_t xbytes = (size_t)C_CH * N_NODES * W_OUTF * sizeof(float);  // 51.2 MB
    float* Xp    = (float*)(ws + off); off += xbytes;
    float* Hc    = (float*)(ws + off); off += xbytes;
    unsigned long long* records = (unsigned long long*)(ws + off);
    off += (size_t)M_TGT * MAXDEG * sizeof(unsigned long long);       // 15.4 MB
    short* Bt    = (short*)(ws + off); off += (size_t)C_CH * W_OUTF * W_INF * sizeof(short);
    int*   rid   = (int*)  (ws + off); off += (size_t)N_NODES * sizeof(int);
    int*   row_list = (int*)(ws + off); off += (size_t)M_TGT * sizeof(int);
    int*   counts   = (int*)(ws + off); off += (size_t)M_TGT * sizeof(int);
    int*   nrows    = (int*)(ws + off); off += 256;

    hipMemsetAsync(rid, 0xFF, (size_t)N_NODES * sizeof(int), stream);   // -1
    hipMemsetAsync(counts, 0, (size_t)M_TGT * sizeof(int), stream);
    hipMemsetAsync(nrows, 0, sizeof(int), stream);
    hipMemsetAsync(d_out, 0, sizeof(float), stream);                    // loss accumulator

    softmax_filt_kernel<<<1, 64, 0, stream>>>(conv_weight, filt);
    wcvt_kernel<<<(C_CH * W_OUTF * W_INF + 255) / 256, 256, 0, stream>>>(Ws, Bt);
    mark_kernel<<<(M_TGT + 255) / 256, 256, 0, stream>>>(target_x, rid);
    compact_kernel<<<(N_NODES + 255) / 256, 256, 0, stream>>>(rid, row_list, nrows);
    dim3 bgrid((E_EDGE / 8 + 255) / 256, T_ET);
    build_kernel<<<bgrid, 256, 0, stream>>>(edge_index, edge_value, rid, counts, records);
    gemm_direct_kernel<<<(N_NODES + 63) / 64, 256, 0, stream>>>(X, Bt, Xp);
    gather_kernel<<<M_TGT, 256, 0, stream>>>(row_list, counts, records, filt, Xp, Hc, nrows);
    head_kernel<<<M_TGT / HTGT, 256, 0, stream>>>(Xp, Hc, linear1_W, linear1_b, lin_W, lin_b,
                                                  target_x, target, out);
}

// Round 7
// 367.174 us; speedup vs baseline: 1.0656x; 1.0656x over previous
//
#include <hip/hip_runtime.h>

#define N_NODES 100000
#define W_INF   256
#define W_OUTF  64
#define C_CH    2
#define T_ET    4
#define E_EDGE  800000
#define NUM_CLS 4
#define M_TGT   20000
#define BETA    0.5f
#define MAXDEG  96

typedef __attribute__((ext_vector_type(8))) short bf16x8;
typedef __attribute__((ext_vector_type(4))) float floatx4;

__device__ inline short f2bf(float f) {
    unsigned u = __builtin_bit_cast(unsigned, f);
    u += 0x7FFF + ((u >> 16) & 1);          // RNE
    return (short)(u >> 16);
}

// ---------- filt = softmax(conv_weight, axis=1) ----------
__global__ void softmax_filt_kernel(const float* __restrict__ conv_weight,
                                    float* __restrict__ filt) {
    int c = threadIdx.x;
    if (c < C_CH) {
        float mx = -1e30f;
        for (int t = 0; t < T_ET; t++) mx = fmaxf(mx, conv_weight[c * T_ET + t]);
        float e[T_ET];
        float s = 0.f;
        for (int t = 0; t < T_ET; t++) { e[t] = expf(conv_weight[c * T_ET + t] - mx); s += e[t]; }
        for (int t = 0; t < T_ET; t++) filt[c * T_ET + t] = e[t] / s;
    }
}

// ---------- Bt[co][k] = bf16(Ws[c][k][o]), co = c*64+o ----------
__global__ void wcvt_kernel(const float* __restrict__ Ws, short* __restrict__ Bt) {
    int i = blockIdx.x * 256 + threadIdx.x;
    if (i < C_CH * W_OUTF * W_INF) {
        int co = i >> 8, k = i & 255;
        int c = co >> 6, o = co & 63;
        Bt[i] = f2bf(Ws[((size_t)c * W_INF + k) * W_OUTF + o]);
    }
}

// ---------- mark rid[target_x[i]] = -2 (rid pre-memset to -1) ----------
__global__ void mark_kernel(const int* __restrict__ target_x, int* __restrict__ rid) {
    int i = blockIdx.x * blockDim.x + threadIdx.x;
    if (i < M_TGT) rid[target_x[i]] = -2;
}

// ---------- compact flagged rows: wave-aggregated atomic ----------
__global__ void compact_kernel(int* __restrict__ rid, int* __restrict__ row_list,
                               int* __restrict__ nrows) {
    int n = blockIdx.x * blockDim.x + threadIdx.x;
    int lane = threadIdx.x & 63;
    bool flag = (n < N_NODES) && (rid[n] == -2);
    unsigned long long mask = __ballot(flag);
    int base = 0;
    if (lane == 0 && mask) base = atomicAdd(nrows, __popcll(mask));
    base = __shfl(base, 0);
    if (flag) {
        int id = base + __popcll(mask & ((1ULL << lane) - 1ULL));
        rid[n] = id;
        row_list[id] = n;
    }
}

// ---------- fused build: bin flagged edges into fixed-stride rows ----------
__global__ void build_kernel(const int* __restrict__ edge_index,
                             const float* __restrict__ edge_value,
                             const int* __restrict__ rid,
                             int* __restrict__ counts,
                             unsigned long long* __restrict__ records) {
    int t = blockIdx.y;
    int i = blockIdx.x * 256 + threadIdx.x;          // oct-edge index
    if (i >= E_EDGE / 8) return;
    int e = i * 8;
    const int*   rbase = &edge_index[(size_t)(t * 2 + 0) * E_EDGE + e];
    const int*   cbase = &edge_index[(size_t)(t * 2 + 1) * E_EDGE + e];
    const float* vbase = &edge_value[(size_t)t * E_EDGE + e];
    int4   r4a = *(const int4*)  &rbase[0], r4b = *(const int4*)  &rbase[4];
    int4   c4a = *(const int4*)  &cbase[0], c4b = *(const int4*)  &cbase[4];
    float4 v4a = *(const float4*)&vbase[0], v4b = *(const float4*)&vbase[4];
    int rows[8] = {r4a.x, r4a.y, r4a.z, r4a.w, r4b.x, r4b.y, r4b.z, r4b.w};
    int cols[8] = {c4a.x, c4a.y, c4a.z, c4a.w, c4b.x, c4b.y, c4b.z, c4b.w};
    float evv[8] = {v4a.x, v4a.y, v4a.z, v4a.w, v4b.x, v4b.y, v4b.z, v4b.w};
    int ids[8];
    #pragma unroll
    for (int j = 0; j < 8; j++) ids[j] = rid[rows[j]];
    #pragma unroll
    for (int j = 0; j < 8; j++) {
        if (ids[j] >= 0) {
            int p = atomicAdd(&counts[ids[j]], 1);
            if (p < MAXDEG) {
                unsigned long long rec =
                    (unsigned long long)(unsigned)(cols[j] | (t << 20)) |
                    ((unsigned long long)__float_as_uint(evv[j]) << 32);
                records[(size_t)ids[j] * MAXDEG + p] = rec;
            }
        }
    }
}

// ---------- gather: Hc[c][row][lane] = sum_p ev*filt[c][t] * Xp[c][col][lane] ----------
__global__ void gather_kernel(const int* __restrict__ row_list,
                              const int* __restrict__ counts,
                              const unsigned long long* __restrict__ records,
                              const float* __restrict__ filt,
                              const float* __restrict__ Xp,
                              float* __restrict__ Hc,
                              const int* __restrict__ nrows_ptr) {
    int b = blockIdx.x;
    if (b >= *nrows_ptr) return;
    int c = threadIdx.x >> 6, lane = threadIdx.x & 63;
    float f[T_ET];
    #pragma unroll
    for (int t = 0; t < T_ET; t++) f[t] = filt[c * T_ET + t];
    int n = row_list[b];
    int cnt = counts[b]; if (cnt > MAXDEG) cnt = MAXDEG;
    const unsigned long long* rec = records + (size_t)b * MAXDEG;
    const float* xb = Xp + (size_t)c * N_NODES * W_OUTF + lane;
    float acc = 0.f;
    int p = 0;
    for (; p + 3 < cnt; p += 4) {
        unsigned long long r0 = rec[p],     r1 = rec[p + 1];
        unsigned long long r2 = rec[p + 2], r3 = rec[p + 3];
        int k0 = (int)(unsigned)r0, k1 = (int)(unsigned)r1;
        int k2 = (int)(unsigned)r2, k3 = (int)(unsigned)r3;
        float e0 = __uint_as_float((unsigned)(r0 >> 32));
        float e1 = __uint_as_float((unsigned)(r1 >> 32));
        float e2 = __uint_as_float((unsigned)(r2 >> 32));
        float e3 = __uint_as_float((unsigned)(r3 >> 32));
        float x0 = xb[(size_t)(k0 & 0xFFFFF) * W_OUTF];
        float x1 = xb[(size_t)(k1 & 0xFFFFF) * W_OUTF];
        float x2 = xb[(size_t)(k2 & 0xFFFFF) * W_OUTF];
        float x3 = xb[(size_t)(k3 & 0xFFFFF) * W_OUTF];
        acc += e0 * f[k0 >> 20] * x0 + e1 * f[k1 >> 20] * x1
             + e2 * f[k2 >> 20] * x2 + e3 * f[k3 >> 20] * x3;
    }
    for (; p < cnt; p++) {
        unsigned long long r0 = rec[p];
        int k0 = (int)(unsigned)r0;
        float e0 = __uint_as_float((unsigned)(r0 >> 32));
        acc += e0 * f[k0 >> 20] * xb[(size_t)(k0 & 0xFFFFF) * W_OUTF];
    }
    Hc[((size_t)c * N_NODES + n) * W_OUTF + lane] = acc;
}

// ---------- MFMA gemm, LDS-staged, 64-row tile (grid 1563, ~5 blocks/CU) ----------
#define MT  64
#define KC  64
#define LDA 72   // 144 B rows: keeps ds_read_b128 16 B-aligned; conflicts measured negligible
__global__ __launch_bounds__(256, 4)
void gemm_mfma_kernel(const float* __restrict__ X, const short* __restrict__ Bt,
                      float* __restrict__ Xp) {
    __shared__ short Al[MT][LDA];     // 9.2 KB
    __shared__ short Bl[128][LDA];    // 18.4 KB
    int tid = threadIdx.x;
    int w = tid >> 6;        // wave 0..3 -> 16-row strip
    int lane = tid & 63;
    int quad = lane >> 4;
    int l15 = lane & 15;
    int n0 = blockIdx.x * MT;
    floatx4 acc[8] = {};
    for (int k0 = 0; k0 < W_INF; k0 += KC) {
        // stage A: 64 rows x 64 k, fp32 -> bf16 (1024 float4-tasks, 4 iters)
        #pragma unroll
        for (int l = 0; l < 4; l++) {
            int idx = tid + l * 256;
            int m = idx >> 4;
            int kp = (idx & 15) * 4;
            int n = n0 + m;
            float4 v = (n < N_NODES) ? *(const float4*)&X[(size_t)n * W_INF + k0 + kp]
                                     : make_float4(0.f, 0.f, 0.f, 0.f);
            short4 sv = make_short4(f2bf(v.x), f2bf(v.y), f2bf(v.z), f2bf(v.w));
            *(short4*)&Al[m][kp] = sv;
        }
        // stage B: 128 co x 64 k bf16 (2048 short4-tasks, 8 iters)
        #pragma unroll
        for (int l = 0; l < 8; l++) {
            int idx = tid + l * 256;
            int nn = idx >> 4;
            int kp = (idx & 15) * 4;
            *(short4*)&Bl[nn][kp] = *(const short4*)&Bt[(size_t)nn * W_INF + k0 + kp];
        }
        __syncthreads();
        #pragma unroll
        for (int kk = 0; kk < KC; kk += 32) {
            int kb = kk + quad * 8;
            bf16x8 a = *(bf16x8*)&Al[w * 16 + l15][kb];
            #pragma unroll
            for (int nt = 0; nt < 8; nt++) {
                bf16x8 b = *(bf16x8*)&Bl[nt * 16 + l15][kb];
                acc[nt] = __builtin_amdgcn_mfma_f32_16x16x32_bf16(a, b, acc[nt], 0, 0, 0);
            }
        }
        __syncthreads();
    }
    // epilogue: D[m][co], m = n0 + w*16 + quad*4 + r, co = nt*16 + l15
    #pragma unroll
    for (int nt = 0; nt < 8; nt++) {
        int co = nt * 16 + l15;
        int c = co >> 6, o = co & 63;
        #pragma unroll
        for (int r = 0; r < 4; r++) {
            int m = n0 + w * 16 + quad * 4 + r;
            if (m < N_NODES)
                Xp[((size_t)c * N_NODES + m) * W_OUTF + o] = acc[nt][r];
        }
    }
}

// ---------- head: 16 targets per block; W1 staged transposed in LDS ----------
#define HTGT 16
__global__ void head_kernel(const float* __restrict__ Xp,
                            const float* __restrict__ Hc,
                            const float* __restrict__ W1,
                            const float* __restrict__ b1,
                            const float* __restrict__ linW,
                            const float* __restrict__ linb,
                            const int* __restrict__ target_x,
                            const int* __restrict__ target,
                            float* __restrict__ out) {
    __shared__ float w1s[C_CH * W_OUTF][W_OUTF + 1];
    __shared__ float hcat_s[4][C_CH * W_OUTF];
    __shared__ float loss_s[4];
    int tid = threadIdx.x;
    for (int i = tid; i < W_OUTF * C_CH * W_OUTF; i += 256) {
        int o = i >> 7, k = i & 127;
        w1s[k][o] = W1[i];
    }
    int wave = tid >> 6, lane = tid & 63;
    float l0 = linW[0 * W_OUTF + lane], l1 = linW[1 * W_OUTF + lane];
    float l2 = linW[2 * W_OUTF + lane], l3 = linW[3 * W_OUTF + lane];
    float lb0 = linb[0], lb1 = linb[1], lb2 = linb[2], lb3 = linb[3];
    float bias = b1[lane];
    float lsum = 0.f;
    __syncthreads();
    for (int it = 0; it < HTGT / 4; it++) {
        int m = blockIdx.x * HTGT + it * 4 + wave;
        int row = target_x[m];
        #pragma unroll
        for (int c = 0; c < C_CH; c++) {
            size_t idx = ((size_t)c * N_NODES + row) * W_OUTF + lane;
            float v = BETA * Xp[idx] + (1.f - BETA) * Hc[idx];
            hcat_s[wave][c * W_OUTF + lane] = fmaxf(v, 0.f);
        }
        __syncthreads();
        float acc = bias;
        #pragma unroll 8
        for (int k = 0; k < C_CH * W_OUTF; k++) acc += hcat_s[wave][k] * w1s[k][lane];
        float h2 = fmaxf(acc, 0.f);
        float p0 = l0 * h2, p1 = l1 * h2, p2 = l2 * h2, p3 = l3 * h2;
        #pragma unroll
        for (int off = 32; off > 0; off >>= 1) {
            p0 += __shfl_xor(p0, off);
            p1 += __shfl_xor(p1, off);
            p2 += __shfl_xor(p2, off);
            p3 += __shfl_xor(p3, off);
        }
        if (lane == 0) {
            float y[NUM_CLS];
            y[0] = p0 + lb0; y[1] = p1 + lb1; y[2] = p2 + lb2; y[3] = p3 + lb3;
            float mx = fmaxf(fmaxf(y[0], y[1]), fmaxf(y[2], y[3]));
            float s = 0.f;
            #pragma unroll
            for (int k = 0; k < NUM_CLS; k++) s += expf(y[k] - mx);
            float lse = mx + logf(s);
            #pragma unroll
            for (int k = 0; k < NUM_CLS; k++) out[1 + (size_t)m * NUM_CLS + k] = y[k];
            int tg = target[m];
            lsum += lse - y[tg];
        }
        __syncthreads();
    }
    if (lane == 0) loss_s[wave] = lsum;
    __syncthreads();
    if (tid == 0) {
        float L = loss_s[0] + loss_s[1] + loss_s[2] + loss_s[3];
        atomicAdd(&out[0], L * (1.0f / (float)M_TGT));
    }
}

extern "C" void kernel_launch(void* const* d_in, const int* in_sizes, int n_in,
                              void* d_out, int out_size, void* d_ws, size_t ws_size,
                              hipStream_t stream) {
    const float* X           = (const float*)d_in[0];
    const float* edge_value  = (const float*)d_in[1];
    const float* Ws          = (const float*)d_in[2];
    const float* conv_weight = (const float*)d_in[3];
    const float* linear1_W   = (const float*)d_in[4];
    const float* linear1_b   = (const float*)d_in[5];
    const float* lin_W       = (const float*)d_in[6];
    const float* lin_b       = (const float*)d_in[7];
    const int*   edge_index  = (const int*)d_in[8];
    const int*   target_x    = (const int*)d_in[9];
    const int*   target      = (const int*)d_in[10];
    float* out = (float*)d_out;

    char* ws = (char*)d_ws;
    size_t off = 0;
    float* filt  = (float*)(ws + off); off += 256;
    size_t xbytes = (size_t)C_CH * N_NODES * W_OUTF * sizeof(float);  // 51.2 MB
    float* Xp    = (float*)(ws + off); off += xbytes;
    float* Hc    = (float*)(ws + off); off += xbytes;
    unsigned long long* records = (unsigned long long*)(ws + off);
    off += (size_t)M_TGT * MAXDEG * sizeof(unsigned long long);       // 15.4 MB
    short* Bt    = (short*)(ws + off); off += (size_t)C_CH * W_OUTF * W_INF * sizeof(short);
    int*   rid   = (int*)  (ws + off); off += (size_t)N_NODES * sizeof(int);
    int*   row_list = (int*)(ws + off); off += (size_t)M_TGT * sizeof(int);
    int*   counts   = (int*)(ws + off); off += (size_t)M_TGT * sizeof(int);
    int*   nrows    = (int*)(ws + off); off += 256;

    hipMemsetAsync(rid, 0xFF, (size_t)N_NODES * sizeof(int), stream);   // -1
    hipMemsetAsync(counts, 0, (size_t)M_TGT * sizeof(int), stream);
    hipMemsetAsync(nrows, 0, sizeof(int), stream);
    hipMemsetAsync(d_out, 0, sizeof(float), stream);                    // loss accumulator

    softmax_filt_kernel<<<1, 64, 0, stream>>>(conv_weight, filt);
    wcvt_kernel<<<(C_CH * W_OUTF * W_INF + 255) / 256, 256, 0, stream>>>(Ws, Bt);
    mark_kernel<<<(M_TGT + 255) / 256, 256, 0, stream>>>(target_x, rid);
    compact_kernel<<<(N_NODES + 255) / 256, 256, 0, stream>>>(rid, row_list, nrows);
    dim3 bgrid((E_EDGE / 8 + 255) / 256, T_ET);
    build_kernel<<<bgrid, 256, 0, stream>>>(edge_index, edge_value, rid, counts, records);
    gemm_mfma_kernel<<<(N_NODES + MT - 1) / MT, 256, 0, stream>>>(X, Bt, Xp);
    gather_kernel<<<M_TGT, 128, 0, stream>>>(row_list, counts, records, filt, Xp, Hc, nrows);
    head_kernel<<<M_TGT / HTGT, 256, 0, stream>>>(Xp, Hc, linear1_W, linear1_b, lin_W, lin_b,
                                                  target_x, target, out);
}

// Round 8
// 357.558 us; speedup vs baseline: 1.0943x; 1.0269x over previous
//
#include <hip/hip_runtime.h>

#define N_NODES 100000
#define W_INF   256
#define W_OUTF  64
#define C_CH    2
#define T_ET    4
#define E_EDGE  800000
#define NUM_CLS 4
#define M_TGT   20000
#define BETA    0.5f
#define MAXDEG  96

typedef __attribute__((ext_vector_type(8))) short bf16x8;
typedef __attribute__((ext_vector_type(4))) float floatx4;

__device__ inline short f2bf(float f) {
    unsigned u = __builtin_bit_cast(unsigned, f);
    u += 0x7FFF + ((u >> 16) & 1);          // RNE
    return (short)(u >> 16);
}

// ---------- wcvt + filt fused: Bt[co][k] = bf16(Ws[c][k][o]); filt = softmax ----------
__global__ void wcvt_kernel(const float* __restrict__ Ws,
                            const float* __restrict__ conv_weight,
                            short* __restrict__ Bt, float* __restrict__ filt) {
    int i = blockIdx.x * 256 + threadIdx.x;
    if (i < C_CH) {   // softmax over edge types for channel i
        int c = i;
        float mx = -1e30f;
        for (int t = 0; t < T_ET; t++) mx = fmaxf(mx, conv_weight[c * T_ET + t]);
        float e[T_ET];
        float s = 0.f;
        for (int t = 0; t < T_ET; t++) { e[t] = expf(conv_weight[c * T_ET + t] - mx); s += e[t]; }
        for (int t = 0; t < T_ET; t++) filt[c * T_ET + t] = e[t] / s;
    }
    if (i < C_CH * W_OUTF * W_INF) {
        int co = i >> 8, k = i & 255;
        int c = co >> 6, o = co & 63;
        Bt[i] = f2bf(Ws[((size_t)c * W_INF + k) * W_OUTF + o]);
    }
}

// ---------- mark rid[target_x[i]] = -2 (rid pre-memset to -1) ----------
__global__ void mark_kernel(const int* __restrict__ target_x, int* __restrict__ rid) {
    int i = blockIdx.x * blockDim.x + threadIdx.x;
    if (i < M_TGT) rid[target_x[i]] = -2;
}

// ---------- compact flagged rows: wave-aggregated atomic ----------
__global__ void compact_kernel(int* __restrict__ rid, int* __restrict__ row_list,
                               int* __restrict__ nrows) {
    int n = blockIdx.x * blockDim.x + threadIdx.x;
    int lane = threadIdx.x & 63;
    bool flag = (n < N_NODES) && (rid[n] == -2);
    unsigned long long mask = __ballot(flag);
    int base = 0;
    if (lane == 0 && mask) base = atomicAdd(nrows, __popcll(mask));
    base = __shfl(base, 0);
    if (flag) {
        int id = base + __popcll(mask & ((1ULL << lane) - 1ULL));
        rid[n] = id;
        row_list[id] = n;
    }
}

// ---------- fused build: bin flagged edges into fixed-stride rows ----------
__global__ void build_kernel(const int* __restrict__ edge_index,
                             const float* __restrict__ edge_value,
                             const int* __restrict__ rid,
                             int* __restrict__ counts,
                             unsigned long long* __restrict__ records) {
    int t = blockIdx.y;
    int i = blockIdx.x * 256 + threadIdx.x;          // oct-edge index
    if (i >= E_EDGE / 8) return;
    int e = i * 8;
    const int*   rbase = &edge_index[(size_t)(t * 2 + 0) * E_EDGE + e];
    const int*   cbase = &edge_index[(size_t)(t * 2 + 1) * E_EDGE + e];
    const float* vbase = &edge_value[(size_t)t * E_EDGE + e];
    int4   r4a = *(const int4*)  &rbase[0], r4b = *(const int4*)  &rbase[4];
    int4   c4a = *(const int4*)  &cbase[0], c4b = *(const int4*)  &cbase[4];
    float4 v4a = *(const float4*)&vbase[0], v4b = *(const float4*)&vbase[4];
    int rows[8] = {r4a.x, r4a.y, r4a.z, r4a.w, r4b.x, r4b.y, r4b.z, r4b.w};
    int cols[8] = {c4a.x, c4a.y, c4a.z, c4a.w, c4b.x, c4b.y, c4b.z, c4b.w};
    float evv[8] = {v4a.x, v4a.y, v4a.z, v4a.w, v4b.x, v4b.y, v4b.z, v4b.w};
    int ids[8];
    #pragma unroll
    for (int j = 0; j < 8; j++) ids[j] = rid[rows[j]];
    #pragma unroll
    for (int j = 0; j < 8; j++) {
        if (ids[j] >= 0) {
            int p = atomicAdd(&counts[ids[j]], 1);
            if (p < MAXDEG) {
                unsigned long long rec =
                    (unsigned long long)(unsigned)(cols[j] | (t << 20)) |
                    ((unsigned long long)__float_as_uint(evv[j]) << 32);
                records[(size_t)ids[j] * MAXDEG + p] = rec;
            }
        }
    }
}

// ---------- gather + relu fuse: Hcat[id][c*64+lane] = relu(B*Xp + (1-B)*Hc) ----------
__global__ void gather_kernel(const int* __restrict__ row_list,
                              const int* __restrict__ counts,
                              const unsigned long long* __restrict__ records,
                              const float* __restrict__ filt,
                              const float* __restrict__ Xp,
                              float* __restrict__ Hcat,
                              const int* __restrict__ nrows_ptr) {
    int b = blockIdx.x;
    if (b >= *nrows_ptr) return;
    int c = threadIdx.x >> 6, lane = threadIdx.x & 63;
    float f[T_ET];
    #pragma unroll
    for (int t = 0; t < T_ET; t++) f[t] = filt[c * T_ET + t];
    int n = row_list[b];
    int cnt = counts[b]; if (cnt > MAXDEG) cnt = MAXDEG;
    const unsigned long long* rec = records + (size_t)b * MAXDEG;
    const float* xb = Xp + (size_t)c * N_NODES * W_OUTF + lane;
    float acc = 0.f;
    int p = 0;
    for (; p + 3 < cnt; p += 4) {
        unsigned long long r0 = rec[p],     r1 = rec[p + 1];
        unsigned long long r2 = rec[p + 2], r3 = rec[p + 3];
        int k0 = (int)(unsigned)r0, k1 = (int)(unsigned)r1;
        int k2 = (int)(unsigned)r2, k3 = (int)(unsigned)r3;
        float e0 = __uint_as_float((unsigned)(r0 >> 32));
        float e1 = __uint_as_float((unsigned)(r1 >> 32));
        float e2 = __uint_as_float((unsigned)(r2 >> 32));
        float e3 = __uint_as_float((unsigned)(r3 >> 32));
        float x0 = xb[(size_t)(k0 & 0xFFFFF) * W_OUTF];
        float x1 = xb[(size_t)(k1 & 0xFFFFF) * W_OUTF];
        float x2 = xb[(size_t)(k2 & 0xFFFFF) * W_OUTF];
        float x3 = xb[(size_t)(k3 & 0xFFFFF) * W_OUTF];
        acc += e0 * f[k0 >> 20] * x0 + e1 * f[k1 >> 20] * x1
             + e2 * f[k2 >> 20] * x2 + e3 * f[k3 >> 20] * x3;
    }
    for (; p < cnt; p++) {
        unsigned long long r0 = rec[p];
        int k0 = (int)(unsigned)r0;
        float e0 = __uint_as_float((unsigned)(r0 >> 32));
        acc += e0 * f[k0 >> 20] * xb[(size_t)(k0 & 0xFFFFF) * W_OUTF];
    }
    float xp = xb[(size_t)n * W_OUTF];
    float v = BETA * xp + (1.f - BETA) * acc;
    Hcat[(size_t)b * (C_CH * W_OUTF) + c * W_OUTF + lane] = fmaxf(v, 0.f);
}

// ---------- barrier-free MFMA gemm: B fully LDS-resident, waves independent ----------
// block = 256 thr = 4 waves; each wave: 16 rows x full N=128, K=256.
#define GMT  64
#define BLDA 264   // shorts per B row (256 + 8): ds_read_b128 -> 2-way conflict (free)
__global__ __launch_bounds__(256, 2)
void gemm_mfma_kernel(const float* __restrict__ X, const short* __restrict__ Bt,
                      float* __restrict__ Xp) {
    __shared__ short Bl[128][BLDA];     // 67.6 KB -> 2 blocks/CU
    int tid = threadIdx.x;
    int w = tid >> 6, lane = tid & 63;
    int quad = lane >> 4, l15 = lane & 15;
    // stage all of B once: 128 co x 256 k bf16 (4096 16B-tasks)
    #pragma unroll
    for (int l = 0; l < 16; l++) {
        int idx = tid + l * 256;
        int r = idx >> 5;
        int kp = (idx & 31) * 8;
        *(bf16x8*)&Bl[r][kp] = *(const bf16x8*)&Bt[(size_t)r * W_INF + kp];
    }
    __syncthreads();
    int m0 = blockIdx.x * GMT + w * 16;
    int arow = m0 + l15;
    if (arow >= N_NODES) arow = N_NODES - 1;
    const float* xrow = X + (size_t)arow * W_INF;
    floatx4 acc[8] = {};
    #pragma unroll
    for (int kc = 0; kc < 8; kc++) {
        int kb = kc * 32 + quad * 8;
        float4 av0 = *(const float4*)&xrow[kb];
        float4 av1 = *(const float4*)&xrow[kb + 4];
        bf16x8 a;
        a[0] = f2bf(av0.x); a[1] = f2bf(av0.y); a[2] = f2bf(av0.z); a[3] = f2bf(av0.w);
        a[4] = f2bf(av1.x); a[5] = f2bf(av1.y); a[6] = f2bf(av1.z); a[7] = f2bf(av1.w);
        #pragma unroll
        for (int nt = 0; nt < 8; nt++) {
            bf16x8 b = *(bf16x8*)&Bl[nt * 16 + l15][kb];
            acc[nt] = __builtin_amdgcn_mfma_f32_16x16x32_bf16(a, b, acc[nt], 0, 0, 0);
        }
    }
    // D layout: co = nt*16 + l15; m = m0 + quad*4 + r
    #pragma unroll
    for (int nt = 0; nt < 8; nt++) {
        int co = nt * 16 + l15;
        int c = co >> 6, o = co & 63;
        #pragma unroll
        for (int r = 0; r < 4; r++) {
            int m = m0 + quad * 4 + r;
            if (m < N_NODES)
                Xp[((size_t)c * N_NODES + m) * W_OUTF + o] = acc[nt][r];
        }
    }
}

// ---------- head: reads compacted Hcat via rid ----------
#define HTGT 16
__global__ void head_kernel(const float* __restrict__ Hcat,
                            const int* __restrict__ rid,
                            const float* __restrict__ W1,
                            const float* __restrict__ b1,
                            const float* __restrict__ linW,
                            const float* __restrict__ linb,
                            const int* __restrict__ target_x,
                            const int* __restrict__ target,
                            float* __restrict__ out) {
    __shared__ float w1s[C_CH * W_OUTF][W_OUTF + 1];
    __shared__ float hcat_s[4][C_CH * W_OUTF];
    __shared__ float loss_s[4];
    int tid = threadIdx.x;
    for (int i = tid; i < W_OUTF * C_CH * W_OUTF; i += 256) {
        int o = i >> 7, k = i & 127;
        w1s[k][o] = W1[i];
    }
    int wave = tid >> 6, lane = tid & 63;
    float l0 = linW[0 * W_OUTF + lane], l1 = linW[1 * W_OUTF + lane];
    float l2 = linW[2 * W_OUTF + lane], l3 = linW[3 * W_OUTF + lane];
    float lb0 = linb[0], lb1 = linb[1], lb2 = linb[2], lb3 = linb[3];
    float bias = b1[lane];
    float lsum = 0.f;
    __syncthreads();
    for (int it = 0; it < HTGT / 4; it++) {
        int m = blockIdx.x * HTGT + it * 4 + wave;
        int row = target_x[m];
        int id = rid[row];
        hcat_s[wave][lane]      = Hcat[(size_t)id * (C_CH * W_OUTF) + lane];
        hcat_s[wave][64 + lane] = Hcat[(size_t)id * (C_CH * W_OUTF) + 64 + lane];
        __syncthreads();
        float acc = bias;
        #pragma unroll 8
        for (int k = 0; k < C_CH * W_OUTF; k++) acc += hcat_s[wave][k] * w1s[k][lane];
        float h2 = fmaxf(acc, 0.f);
        float p0 = l0 * h2, p1 = l1 * h2, p2 = l2 * h2, p3 = l3 * h2;
        #pragma unroll
        for (int off = 32; off > 0; off >>= 1) {
            p0 += __shfl_xor(p0, off);
            p1 += __shfl_xor(p1, off);
            p2 += __shfl_xor(p2, off);
            p3 += __shfl_xor(p3, off);
        }
        if (lane == 0) {
            float y[NUM_CLS];
            y[0] = p0 + lb0; y[1] = p1 + lb1; y[2] = p2 + lb2; y[3] = p3 + lb3;
            float mx = fmaxf(fmaxf(y[0], y[1]), fmaxf(y[2], y[3]));
            float s = 0.f;
            #pragma unroll
            for (int k = 0; k < NUM_CLS; k++) s += expf(y[k] - mx);
            float lse = mx + logf(s);
            #pragma unroll
            for (int k = 0; k < NUM_CLS; k++) out[1 + (size_t)m * NUM_CLS + k] = y[k];
            int tg = target[m];
            lsum += lse - y[tg];
        }
        __syncthreads();
    }
    if (lane == 0) loss_s[wave] = lsum;
    __syncthreads();
    if (tid == 0) {
        float L = loss_s[0] + loss_s[1] + loss_s[2] + loss_s[3];
        atomicAdd(&out[0], L * (1.0f / (float)M_TGT));
    }
}

extern "C" void kernel_launch(void* const* d_in, const int* in_sizes, int n_in,
                              void* d_out, int out_size, void* d_ws, size_t ws_size,
                              hipStream_t stream) {
    const float* X           = (const float*)d_in[0];
    const float* edge_value  = (const float*)d_in[1];
    const float* Ws          = (const float*)d_in[2];
    const float* conv_weight = (const float*)d_in[3];
    const float* linear1_W   = (const float*)d_in[4];
    const float* linear1_b   = (const float*)d_in[5];
    const float* lin_W       = (const float*)d_in[6];
    const float* lin_b       = (const float*)d_in[7];
    const int*   edge_index  = (const int*)d_in[8];
    const int*   target_x    = (const int*)d_in[9];
    const int*   target      = (const int*)d_in[10];
    float* out = (float*)d_out;

    char* ws = (char*)d_ws;
    size_t off = 0;
    float* filt  = (float*)(ws + off); off += 256;
    size_t xbytes = (size_t)C_CH * N_NODES * W_OUTF * sizeof(float);  // 51.2 MB
    float* Xp    = (float*)(ws + off); off += xbytes;
    float* Hcat  = (float*)(ws + off); off += (size_t)M_TGT * C_CH * W_OUTF * sizeof(float);
    unsigned long long* records = (unsigned long long*)(ws + off);
    off += (size_t)M_TGT * MAXDEG * sizeof(unsigned long long);       // 15.4 MB
    short* Bt    = (short*)(ws + off); off += (size_t)C_CH * W_OUTF * W_INF * sizeof(short);
    int*   rid   = (int*)  (ws + off); off += (size_t)N_NODES * sizeof(int);
    int*   row_list = (int*)(ws + off); off += (size_t)M_TGT * sizeof(int);
    int*   counts   = (int*)(ws + off); off += (size_t)M_TGT * sizeof(int);
    int*   nrows    = (int*)(ws + off); off += 256;

    hipMemsetAsync(rid, 0xFF, (size_t)N_NODES * sizeof(int), stream);   // -1
    hipMemsetAsync(counts, 0, (size_t)M_TGT * sizeof(int), stream);
    hipMemsetAsync(nrows, 0, sizeof(int), stream);
    hipMemsetAsync(d_out, 0, sizeof(float), stream);                    // loss accumulator

    wcvt_kernel<<<(C_CH * W_OUTF * W_INF + 255) / 256, 256, 0, stream>>>(Ws, conv_weight, Bt, filt);
    mark_kernel<<<(M_TGT + 255) / 256, 256, 0, stream>>>(target_x, rid);
    compact_kernel<<<(N_NODES + 255) / 256, 256, 0, stream>>>(rid, row_list, nrows);
    dim3 bgrid((E_EDGE / 8 + 255) / 256, T_ET);
    build_kernel<<<bgrid, 256, 0, stream>>>(edge_index, edge_value, rid, counts, records);
    gemm_mfma_kernel<<<(N_NODES + GMT - 1) / GMT, 256, 0, stream>>>(X, Bt, Xp);
    gather_kernel<<<M_TGT, 128, 0, stream>>>(row_list, counts, records, filt, Xp, Hcat, nrows);
    head_kernel<<<M_TGT / HTGT, 256, 0, stream>>>(Hcat, rid, linear1_W, linear1_b, lin_W, lin_b,
                                                  target_x, target, out);
}

// Round 9
// 340.245 us; speedup vs baseline: 1.1500x; 1.0509x over previous
//
#include <hip/hip_runtime.h>

#define N_NODES 100000
#define W_INF   256
#define W_OUTF  64
#define C_CH    2
#define T_ET    4
#define E_EDGE  800000
#define NUM_CLS 4
#define M_TGT   20000
#define BETA    0.5f
#define MAXDEG  96

typedef __attribute__((ext_vector_type(8))) short bf16x8;
typedef __attribute__((ext_vector_type(4))) float floatx4;

__device__ inline short f2bf(float f) {
    unsigned u = __builtin_bit_cast(unsigned, f);
    u += 0x7FFF + ((u >> 16) & 1);          // RNE
    return (short)(u >> 16);
}

// ---------- setup: softmax(filt) + Bt convert + mark rid + zero scalars ----------
// grid = 128 blocks x 256 (covers 32768 wcvt elements; first 20000 also mark).
__global__ void setup_kernel(const float* __restrict__ Ws,
                             const float* __restrict__ conv_weight,
                             const int* __restrict__ target_x,
                             short* __restrict__ Bt, float* __restrict__ filt,
                             int* __restrict__ rid, int* __restrict__ nrows,
                             float* __restrict__ out) {
    int i = blockIdx.x * 256 + threadIdx.x;
    if (i == 0) { *nrows = 0; out[0] = 0.f; }
    if (i < C_CH) {
        int c = i;
        float mx = -1e30f;
        for (int t = 0; t < T_ET; t++) mx = fmaxf(mx, conv_weight[c * T_ET + t]);
        float e[T_ET];
        float s = 0.f;
        for (int t = 0; t < T_ET; t++) { e[t] = expf(conv_weight[c * T_ET + t] - mx); s += e[t]; }
        for (int t = 0; t < T_ET; t++) filt[c * T_ET + t] = e[t] / s;
    }
    if (i < C_CH * W_OUTF * W_INF) {
        int co = i >> 8, k = i & 255;
        int c = co >> 6, o = co & 63;
        Bt[i] = f2bf(Ws[((size_t)c * W_INF + k) * W_OUTF + o]);
    }
    if (i < M_TGT) rid[target_x[i]] = -2;
}

// ---------- compact flagged rows (wave-aggregated atomic) + zero counts ----------
__global__ void compact_kernel(int* __restrict__ rid, int* __restrict__ row_list,
                               int* __restrict__ nrows, int* __restrict__ counts) {
    int n = blockIdx.x * blockDim.x + threadIdx.x;
    if (n < M_TGT) counts[n] = 0;          // consumed by build_kernel (next dispatch)
    int lane = threadIdx.x & 63;
    bool flag = (n < N_NODES) && (rid[n] == -2);
    unsigned long long mask = __ballot(flag);
    int base = 0;
    if (lane == 0 && mask) base = atomicAdd(nrows, __popcll(mask));
    base = __shfl(base, 0);
    if (flag) {
        int id = base + __popcll(mask & ((1ULL << lane) - 1ULL));
        rid[n] = id;
        row_list[id] = n;
    }
}

// ---------- fused build: bin flagged edges into fixed-stride rows ----------
__global__ void build_kernel(const int* __restrict__ edge_index,
                             const float* __restrict__ edge_value,
                             const int* __restrict__ rid,
                             int* __restrict__ counts,
                             unsigned long long* __restrict__ records) {
    int t = blockIdx.y;
    int i = blockIdx.x * 256 + threadIdx.x;          // oct-edge index
    if (i >= E_EDGE / 8) return;
    int e = i * 8;
    const int*   rbase = &edge_index[(size_t)(t * 2 + 0) * E_EDGE + e];
    const int*   cbase = &edge_index[(size_t)(t * 2 + 1) * E_EDGE + e];
    const float* vbase = &edge_value[(size_t)t * E_EDGE + e];
    int4   r4a = *(const int4*)  &rbase[0], r4b = *(const int4*)  &rbase[4];
    int4   c4a = *(const int4*)  &cbase[0], c4b = *(const int4*)  &cbase[4];
    float4 v4a = *(const float4*)&vbase[0], v4b = *(const float4*)&vbase[4];
    int rows[8] = {r4a.x, r4a.y, r4a.z, r4a.w, r4b.x, r4b.y, r4b.z, r4b.w};
    int cols[8] = {c4a.x, c4a.y, c4a.z, c4a.w, c4b.x, c4b.y, c4b.z, c4b.w};
    float evv[8] = {v4a.x, v4a.y, v4a.z, v4a.w, v4b.x, v4b.y, v4b.z, v4b.w};
    int ids[8];
    #pragma unroll
    for (int j = 0; j < 8; j++) ids[j] = rid[rows[j]];
    #pragma unroll
    for (int j = 0; j < 8; j++) {
        if (ids[j] >= 0) {
            int p = atomicAdd(&counts[ids[j]], 1);
            if (p < MAXDEG) {
                unsigned long long rec =
                    (unsigned long long)(unsigned)(cols[j] | (t << 20)) |
                    ((unsigned long long)__float_as_uint(evv[j]) << 32);
                records[(size_t)ids[j] * MAXDEG + p] = rec;
            }
        }
    }
}

// ---------- MFMA gemm: per-channel B in LDS (33.8 KB), A preloaded in regs ----------
// block = 4 waves; wave = 16 rows x full N=128; K=256. 4 blocks/CU.
#define GMT  64
#define BLDA 264
__global__ __launch_bounds__(256, 4)
void gemm_mfma_kernel(const float* __restrict__ X, const short* __restrict__ Bt,
                      float* __restrict__ Xp) {
    __shared__ short Bl[64][BLDA];     // 33.8 KB
    int tid = threadIdx.x;
    int w = tid >> 6, lane = tid & 63;
    int quad = lane >> 4, l15 = lane & 15;
    int m0 = blockIdx.x * GMT + w * 16;
    int arow = m0 + l15;
    if (arow >= N_NODES) arow = N_NODES - 1;
    const float* xrow = X + (size_t)arow * W_INF;
    // preload + convert the wave's full A strip (8 chunks x 8 bf16 = 32 VGPRs)
    bf16x8 af[8];
    #pragma unroll
    for (int kc = 0; kc < 8; kc++) {
        int kb = kc * 32 + quad * 8;
        float4 v0 = *(const float4*)&xrow[kb];
        float4 v1 = *(const float4*)&xrow[kb + 4];
        af[kc][0] = f2bf(v0.x); af[kc][1] = f2bf(v0.y);
        af[kc][2] = f2bf(v0.z); af[kc][3] = f2bf(v0.w);
        af[kc][4] = f2bf(v1.x); af[kc][5] = f2bf(v1.y);
        af[kc][6] = f2bf(v1.z); af[kc][7] = f2bf(v1.w);
    }
    floatx4 acc[C_CH][4] = {};
    for (int c = 0; c < C_CH; c++) {
        if (c) __syncthreads();   // protect re-stage
        // stage channel c of B: 64 rows x 256 k
        #pragma unroll
        for (int l = 0; l < 8; l++) {
            int idx = tid + l * 256;
            int r = idx >> 5;
            int kp = (idx & 31) * 8;
            *(bf16x8*)&Bl[r][kp] = *(const bf16x8*)&Bt[(size_t)(c * 64 + r) * W_INF + kp];
        }
        __syncthreads();
        #pragma unroll
        for (int kc = 0; kc < 8; kc++) {
            int kb = kc * 32 + quad * 8;
            #pragma unroll
            for (int nt = 0; nt < 4; nt++) {
                bf16x8 b = *(bf16x8*)&Bl[nt * 16 + l15][kb];
                acc[c][nt] = __builtin_amdgcn_mfma_f32_16x16x32_bf16(af[kc], b, acc[c][nt], 0, 0, 0);
            }
        }
    }
    // D layout: o = nt*16 + l15; m = m0 + quad*4 + r
    #pragma unroll
    for (int c = 0; c < C_CH; c++) {
        #pragma unroll
        for (int nt = 0; nt < 4; nt++) {
            int o = nt * 16 + l15;
            #pragma unroll
            for (int r = 0; r < 4; r++) {
                int m = m0 + quad * 4 + r;
                if (m < N_NODES)
                    Xp[((size_t)c * N_NODES + m) * W_OUTF + o] = acc[c][nt][r];
            }
        }
    }
}

// ---------- gather + relu fuse: Hcat[id][c*64+lane] = relu(B*Xp + (1-B)*Hc) ----------
__global__ void gather_kernel(const int* __restrict__ row_list,
                              const int* __restrict__ counts,
                              const unsigned long long* __restrict__ records,
                              const float* __restrict__ filt,
                              const float* __restrict__ Xp,
                              float* __restrict__ Hcat,
                              const int* __restrict__ nrows_ptr) {
    int b = blockIdx.x;
    if (b >= *nrows_ptr) return;
    int c = threadIdx.x >> 6, lane = threadIdx.x & 63;
    float f[T_ET];
    #pragma unroll
    for (int t = 0; t < T_ET; t++) f[t] = filt[c * T_ET + t];
    int n = row_list[b];
    int cnt = counts[b]; if (cnt > MAXDEG) cnt = MAXDEG;
    const unsigned long long* rec = records + (size_t)b * MAXDEG;
    const float* xb = Xp + (size_t)c * N_NODES * W_OUTF + lane;
    float acc = 0.f;
    int p = 0;
    for (; p + 3 < cnt; p += 4) {
        unsigned long long r0 = rec[p],     r1 = rec[p + 1];
        unsigned long long r2 = rec[p + 2], r3 = rec[p + 3];
        int k0 = (int)(unsigned)r0, k1 = (int)(unsigned)r1;
        int k2 = (int)(unsigned)r2, k3 = (int)(unsigned)r3;
        float e0 = __uint_as_float((unsigned)(r0 >> 32));
        float e1 = __uint_as_float((unsigned)(r1 >> 32));
        float e2 = __uint_as_float((unsigned)(r2 >> 32));
        float e3 = __uint_as_float((unsigned)(r3 >> 32));
        float x0 = xb[(size_t)(k0 & 0xFFFFF) * W_OUTF];
        float x1 = xb[(size_t)(k1 & 0xFFFFF) * W_OUTF];
        float x2 = xb[(size_t)(k2 & 0xFFFFF) * W_OUTF];
        float x3 = xb[(size_t)(k3 & 0xFFFFF) * W_OUTF];
        acc += e0 * f[k0 >> 20] * x0 + e1 * f[k1 >> 20] * x1
             + e2 * f[k2 >> 20] * x2 + e3 * f[k3 >> 20] * x3;
    }
    for (; p < cnt; p++) {
        unsigned long long r0 = rec[p];
        int k0 = (int)(unsigned)r0;
        float e0 = __uint_as_float((unsigned)(r0 >> 32));
        acc += e0 * f[k0 >> 20] * xb[(size_t)(k0 & 0xFFFFF) * W_OUTF];
    }
    float xp = xb[(size_t)n * W_OUTF];
    float v = BETA * xp + (1.f - BETA) * acc;
    Hcat[(size_t)b * (C_CH * W_OUTF) + c * W_OUTF + lane] = fmaxf(v, 0.f);
}

// ---------- head: reads compacted Hcat via rid ----------
#define HTGT 16
__global__ void head_kernel(const float* __restrict__ Hcat,
                            const int* __restrict__ rid,
                            const float* __restrict__ W1,
                            const float* __restrict__ b1,
                            const float* __restrict__ linW,
                            const float* __restrict__ linb,
                            const int* __restrict__ target_x,
                            const int* __restrict__ target,
                            float* __restrict__ out) {
    __shared__ float w1s[C_CH * W_OUTF][W_OUTF + 1];
    __shared__ float hcat_s[4][C_CH * W_OUTF];
    __shared__ float loss_s[4];
    int tid = threadIdx.x;
    for (int i = tid; i < W_OUTF * C_CH * W_OUTF; i += 256) {
        int o = i >> 7, k = i & 127;
        w1s[k][o] = W1[i];
    }
    int wave = tid >> 6, lane = tid & 63;
    float l0 = linW[0 * W_OUTF + lane], l1 = linW[1 * W_OUTF + lane];
    float l2 = linW[2 * W_OUTF + lane], l3 = linW[3 * W_OUTF + lane];
    float lb0 = linb[0], lb1 = linb[1], lb2 = linb[2], lb3 = linb[3];
    float bias = b1[lane];
    float lsum = 0.f;
    __syncthreads();
    for (int it = 0; it < HTGT / 4; it++) {
        int m = blockIdx.x * HTGT + it * 4 + wave;
        int row = target_x[m];
        int id = rid[row];
        hcat_s[wave][lane]      = Hcat[(size_t)id * (C_CH * W_OUTF) + lane];
        hcat_s[wave][64 + lane] = Hcat[(size_t)id * (C_CH * W_OUTF) + 64 + lane];
        __syncthreads();
        float acc = bias;
        #pragma unroll 8
        for (int k = 0; k < C_CH * W_OUTF; k++) acc += hcat_s[wave][k] * w1s[k][lane];
        float h2 = fmaxf(acc, 0.f);
        float p0 = l0 * h2, p1 = l1 * h2, p2 = l2 * h2, p3 = l3 * h2;
        #pragma unroll
        for (int off = 32; off > 0; off >>= 1) {
            p0 += __shfl_xor(p0, off);
            p1 += __shfl_xor(p1, off);
            p2 += __shfl_xor(p2, off);
            p3 += __shfl_xor(p3, off);
        }
        if (lane == 0) {
            float y[NUM_CLS];
            y[0] = p0 + lb0; y[1] = p1 + lb1; y[2] = p2 + lb2; y[3] = p3 + lb3;
            float mx = fmaxf(fmaxf(y[0], y[1]), fmaxf(y[2], y[3]));
            float s = 0.f;
            #pragma unroll
            for (int k = 0; k < NUM_CLS; k++) s += expf(y[k] - mx);
            float lse = mx + logf(s);
            #pragma unroll
            for (int k = 0; k < NUM_CLS; k++) out[1 + (size_t)m * NUM_CLS + k] = y[k];
            int tg = target[m];
            lsum += lse - y[tg];
        }
        __syncthreads();
    }
    if (lane == 0) loss_s[wave] = lsum;
    __syncthreads();
    if (tid == 0) {
        float L = loss_s[0] + loss_s[1] + loss_s[2] + loss_s[3];
        atomicAdd(&out[0], L * (1.0f / (float)M_TGT));
    }
}

extern "C" void kernel_launch(void* const* d_in, const int* in_sizes, int n_in,
                              void* d_out, int out_size, void* d_ws, size_t ws_size,
                              hipStream_t stream) {
    const float* X           = (const float*)d_in[0];
    const float* edge_value  = (const float*)d_in[1];
    const float* Ws          = (const float*)d_in[2];
    const float* conv_weight = (const float*)d_in[3];
    const float* linear1_W   = (const float*)d_in[4];
    const float* linear1_b   = (const float*)d_in[5];
    const float* lin_W       = (const float*)d_in[6];
    const float* lin_b       = (const float*)d_in[7];
    const int*   edge_index  = (const int*)d_in[8];
    const int*   target_x    = (const int*)d_in[9];
    const int*   target      = (const int*)d_in[10];
    float* out = (float*)d_out;

    char* ws = (char*)d_ws;
    size_t off = 0;
    float* filt  = (float*)(ws + off); off += 256;
    size_t xbytes = (size_t)C_CH * N_NODES * W_OUTF * sizeof(float);  // 51.2 MB
    float* Xp    = (float*)(ws + off); off += xbytes;
    float* Hcat  = (float*)(ws + off); off += (size_t)M_TGT * C_CH * W_OUTF * sizeof(float);
    unsigned long long* records = (unsigned long long*)(ws + off);
    off += (size_t)M_TGT * MAXDEG * sizeof(unsigned long long);       // 15.4 MB
    short* Bt    = (short*)(ws + off); off += (size_t)C_CH * W_OUTF * W_INF * sizeof(short);
    int*   rid   = (int*)  (ws + off); off += (size_t)N_NODES * sizeof(int);
    int*   row_list = (int*)(ws + off); off += (size_t)M_TGT * sizeof(int);
    int*   counts   = (int*)(ws + off); off += (size_t)M_TGT * sizeof(int);
    int*   nrows    = (int*)(ws + off); off += 256;

    hipMemsetAsync(rid, 0xFF, (size_t)N_NODES * sizeof(int), stream);   // -1 (safety on first launch)

    setup_kernel<<<128, 256, 0, stream>>>(Ws, conv_weight, target_x, Bt, filt, rid, nrows, out);
    compact_kernel<<<(N_NODES + 255) / 256, 256, 0, stream>>>(rid, row_list, nrows, counts);
    dim3 bgrid((E_EDGE / 8 + 255) / 256, T_ET);
    build_kernel<<<bgrid, 256, 0, stream>>>(edge_index, edge_value, rid, counts, records);
    gemm_mfma_kernel<<<(N_NODES + GMT - 1) / GMT, 256, 0, stream>>>(X, Bt, Xp);
    gather_kernel<<<M_TGT, 128, 0, stream>>>(row_list, counts, records, filt, Xp, Hcat, nrows);
    head_kernel<<<M_TGT / HTGT, 256, 0, stream>>>(Hcat, rid, linear1_W, linear1_b, lin_W, lin_b,
                                                  target_x, target, out);
}